// Round 10
// baseline (3733.059 us; speedup 1.0000x reference)
//
#include <hip/hip_runtime.h>

#define T_LEN 16384
#define BATCH 32
#define HID 32
#define L2E 1.44269504088896340736f

typedef float f2 __attribute__((ext_vector_type(2)));

// Force single-instruction transcendentals. r9 evidence: per-CU VALU issue is
// ~80% busy at ~215 inst/step vs ~100 counted in source — the gap matches
// __exp2f / (1.0f/x) fallback expansions (full fp32 div is ~10-14 insts).
// v_exp_f32 / v_rcp_f32 are VOP1, HW-interlocked (no waitcnt), and the
// overflow tail (exp2->inf, rcp->0) is exactly the sigmoid saturation.
__device__ __forceinline__ float exp2_hw(float x) {
    float r;
    asm("v_exp_f32 %0, %1" : "=v"(r) : "v"(x));
    return r;
}
__device__ __forceinline__ float rcp_hw(float x) {
    float r;
    asm("v_rcp_f32 %0, %1" : "=v"(r) : "v"(x));
    return r;
}

__device__ __forceinline__ float rlane(float v, int lane) {
    return __int_as_float(__builtin_amdgcn_readlane(__float_as_int(v), lane));
}
__device__ __forceinline__ unsigned rlane_u(float v, int lane) {
    return (unsigned)__builtin_amdgcn_readlane(__float_as_int(v), lane);
}

// Cross-half exchange (lower->upper), VALU pipe. Convention verified r4/r5:
// builtin returns {vdst_new, vsrc_new}; r.x has lanes 32-63 = old lanes 0-31.
__device__ __forceinline__ float xhalf_lo_to_hi(float v) {
#if __has_builtin(__builtin_amdgcn_permlane32_swap)
    typedef unsigned u2_t __attribute__((ext_vector_type(2)));
    u2_t r = __builtin_amdgcn_permlane32_swap(__float_as_uint(v), __float_as_uint(v),
                                              false, false);
    return __uint_as_float(r.x);
#else
    return __shfl_xor(v, 32, 64);
#endif
}

// r10 = r9 (best: 3640us, VGPR=132, weights resident) with hardware
// v_exp_f32 / v_rcp_f32 forced via asm. One variable changed.
__global__ __launch_bounds__(64) __attribute__((amdgpu_waves_per_eu(1, 1)))
void lstm_seq_kernel(const float* __restrict__ x,
                     const float* __restrict__ W_ih,
                     const float* __restrict__ W_hh,
                     const float* __restrict__ b_ih,
                     const float* __restrict__ b_hh,
                     const float* __restrict__ W_out,
                     const float* __restrict__ b_out,
                     float* __restrict__ out)
{
    const int b    = blockIdx.x;
    const int lane = threadIdx.x;
    const int j    = lane & 31;
    const bool upper = (lane >= 32);

    // torch gate order in W_ih/W_hh rows: [0,32)=i [32,64)=f [64,96)=g [96,128)=o
    const int rowA = upper ? (32 + j) : j;        // f : i   (both sigmoid)
    const int rowB = upper ? (96 + j) : (64 + j); // o : g   (sigmoid : tanh)

    // W rows as float2 pairs (raw values)
    f2 Wa2[16], Wb2[16];
    const f2* ra2 = reinterpret_cast<const f2*>(W_hh + (size_t)rowA * HID);
    const f2* rb2 = reinterpret_cast<const f2*>(W_hh + (size_t)rowB * HID);
    #pragma unroll
    for (int q = 0; q < 16; ++q) { Wa2[q] = ra2[q]; Wb2[q] = rb2[q]; }
    // Pin: with the (1,1) clamp the allocator has 512 regs — keep all 32
    // f2 weight pairs resident for the whole kernel (r9: VGPR=132, works).
    #pragma unroll
    for (int q = 0; q < 16; ++q) { asm("" : "+v"(Wa2[q]), "+v"(Wb2[q])); }

    const float wihA = W_ih[rowA];
    const float wihB = W_ih[rowB];
    const float bA = b_ih[rowA] + b_hh[rowA];
    const float bB = b_ih[rowB] + b_hh[rowB];

    // B-gate activation: r = rcp(1 + exp2(-z*sB)); B = r*mB + aB
    const float sB = upper ? L2E : (2.0f * L2E);
    const float mB = upper ? 1.0f : 2.0f;
    const float aB = upper ? 0.0f : -1.0f;

    const float wout = W_out[j];
    const float bout = b_out[0];

    // phist[s][lane], stride 65: store banks (s+l)%32 conflict-free;
    // flush read phist[l*65+32+k] banks (l+k)%32 conflict-free.
    __shared__ float phist[64 * 65];

    float c = 0.0f, h = 0.0f;   // state lives in upper lanes

    const float* xb = x + (size_t)b * T_LEN;
    float*       yb = out + (size_t)b * T_LEN;

    float xv = xb[lane];  // 64 timesteps of x per lane-chunk

    for (int t0 = 0; t0 < T_LEN; t0 += 64) {
        float xv_next = (t0 + 64 < T_LEN) ? xb[t0 + 64 + lane] : 0.0f;

        #pragma unroll 4
        for (int s = 0; s < 64; ++s) {
            // x contribution: independent of h, schedules off-chain
            const float xs  = rlane(xv, s);
            const float xpA = fmaf(xs, wihA, bA);
            const float xpB = fmaf(xs, wihB, bB);

            // Fused broadcast+dot: per q, read h pair from upper lanes
            // (previous step's h, loop-carried), pack to an SGPR pair,
            // consume in v_pk_fma. First 4 q's start the split accumulators
            // with v_pk_mul (no zero-init movs).
            f2 zA[4], zB[4];
            #pragma unroll
            for (int q = 0; q < 16; ++q) {
                const unsigned lo = rlane_u(h, 32 + 2 * q);
                const unsigned hi = rlane_u(h, 33 + 2 * q);
                const unsigned long long hp =
                    (unsigned long long)lo | ((unsigned long long)hi << 32);
                if (q < 4) {
                    asm("v_pk_mul_f32 %0, %1, %2"
                        : "=v"(zA[q]) : "s"(hp), "v"(Wa2[q]));
                    asm("v_pk_mul_f32 %0, %1, %2"
                        : "=v"(zB[q]) : "s"(hp), "v"(Wb2[q]));
                } else {
                    asm("v_pk_fma_f32 %0, %1, %2, %0"
                        : "+v"(zA[q & 3]) : "s"(hp), "v"(Wa2[q]));
                    asm("v_pk_fma_f32 %0, %1, %2, %0"
                        : "+v"(zB[q & 3]) : "s"(hp), "v"(Wb2[q]));
                }
            }
            const f2 rA = (zA[0] + zA[1]) + (zA[2] + zA[3]);
            const f2 rB = (zB[0] + zB[1]) + (zB[2] + zB[3]);
            const float za = (rA.x + rA.y) + xpA;
            const float zb = (rB.x + rB.y) + xpB;

            // A = sigmoid(za): rcp(1 + exp2(-za*L2E)) — 4 insts, HW ops
            const float A  = rcp_hw(1.0f + exp2_hw(-za * L2E));
            const float r  = rcp_hw(1.0f + exp2_hw(-zb * sB));
            const float Bv = fmaf(r, mB, aB);  // tanh(g) : sigmoid(o)

            const float u  = A * Bv;           // sig(i)*tanh(g) (lower)
            const float tu = xhalf_lo_to_hi(u);

            c = fmaf(A, c, tu);                // sig(f)*c + u (upper lanes valid)
            const float th = fmaf(2.0f, rcp_hw(1.0f + exp2_hw(-2.0f * L2E * c)), -1.0f);
            h = Bv * th;                       // sig(o)*tanh(c)

            phist[s * 65 + lane] = h * wout;   // unconditional, conflict-free
        }

        __syncthreads();  // single wave: cheap; publish phist
        float acc = bout;
        #pragma unroll
        for (int k = 0; k < HID; ++k) acc += phist[lane * 65 + 32 + k];
        yb[t0 + lane] = acc;
        __syncthreads();  // protect phist before next chunk rewrites it

        xv = xv_next;
    }
}

extern "C" void kernel_launch(void* const* d_in, const int* in_sizes, int n_in,
                              void* d_out, int out_size, void* d_ws, size_t ws_size,
                              hipStream_t stream) {
    const float* x     = (const float*)d_in[0];
    const float* W_ih  = (const float*)d_in[1];
    const float* W_hh  = (const float*)d_in[2];
    const float* b_ih  = (const float*)d_in[3];
    const float* b_hh  = (const float*)d_in[4];
    const float* W_out = (const float*)d_in[5];
    const float* b_out = (const float*)d_in[6];
    float* out = (float*)d_out;

    lstm_seq_kernel<<<BATCH, 64, 0, stream>>>(x, W_ih, W_hh, b_ih, b_hh,
                                              W_out, b_out, out);
}

// Round 11
// 3187.994 us; speedup vs baseline: 1.1710x; 1.1710x over previous
//
#include <hip/hip_runtime.h>

#define T_LEN 16384
#define BATCH 32
#define HID 32
#define L2E 1.44269504088896340736f

typedef float f2 __attribute__((ext_vector_type(2)));

#if __has_builtin(__builtin_amdgcn_exp2f)
#define EXP2F(x) __builtin_amdgcn_exp2f(x)
#else
#define EXP2F(x) __exp2f(x)
#endif
#if __has_builtin(__builtin_amdgcn_rcpf)
#define RCPF(x) __builtin_amdgcn_rcpf(x)
#else
#define RCPF(x) (1.0f / (x))
#endif

__device__ __forceinline__ float rlane(float v, int lane) {
    return __int_as_float(__builtin_amdgcn_readlane(__float_as_int(v), lane));
}

// Cross-half exchange (lower->upper), VALU pipe. Convention verified r4/r5:
// builtin returns {vdst_new, vsrc_new}; r.x has lanes 32-63 = old lanes 0-31.
__device__ __forceinline__ float xhalf_lo_to_hi(float v) {
#if __has_builtin(__builtin_amdgcn_permlane32_swap)
    typedef unsigned u2_t __attribute__((ext_vector_type(2)));
    u2_t r = __builtin_amdgcn_permlane32_swap(__float_as_uint(v), __float_as_uint(v),
                                              false, false);
    return __uint_as_float(r.x);
#else
    return __shfl_xor(v, 32, 64);
#endif
}

// r11: LDS-replicated h broadcast replaces the 32-readlane/SGPR path.
// Rationale: a ~350-400 cyc/step cost has been invariant across r1-r10
// (scalar<->pk, reload<->resident, fused<->phased). The only shared hot
// structure is the readlane block feeding SGPR operands. Here: 1 ds_write_b32
// (all 64 lanes -> hbuf[lane]; upper half holds h) + 8 wave-uniform
// ds_read_b128 (broadcast, conflict-free) put all 32 h values in per-lane
// VGPRs; the 32 v_pk_fma_f32 become pure-VGPR (no SGPR write/read hazards,
// no readlanes). Broadcast issue 32 insts -> 10.
__global__ __launch_bounds__(64) __attribute__((amdgpu_waves_per_eu(1, 1)))
void lstm_seq_kernel(const float* __restrict__ x,
                     const float* __restrict__ W_ih,
                     const float* __restrict__ W_hh,
                     const float* __restrict__ b_ih,
                     const float* __restrict__ b_hh,
                     const float* __restrict__ W_out,
                     const float* __restrict__ b_out,
                     float* __restrict__ out)
{
    const int b    = blockIdx.x;
    const int lane = threadIdx.x;
    const int j    = lane & 31;
    const bool upper = (lane >= 32);

    // torch gate order in W_ih/W_hh rows: [0,32)=i [32,64)=f [64,96)=g [96,128)=o
    const int rowA = upper ? (32 + j) : j;        // f : i   (both sigmoid)
    const int rowB = upper ? (96 + j) : (64 + j); // o : g   (sigmoid : tanh)

    // W rows as float2 pairs, pinned resident (r9: VGPR=132, mild win)
    f2 Wa2[16], Wb2[16];
    const f2* ra2 = reinterpret_cast<const f2*>(W_hh + (size_t)rowA * HID);
    const f2* rb2 = reinterpret_cast<const f2*>(W_hh + (size_t)rowB * HID);
    #pragma unroll
    for (int q = 0; q < 16; ++q) { Wa2[q] = ra2[q]; Wb2[q] = rb2[q]; }
    #pragma unroll
    for (int q = 0; q < 16; ++q) { asm("" : "+v"(Wa2[q]), "+v"(Wb2[q])); }

    const float wihA = W_ih[rowA];
    const float wihB = W_ih[rowB];
    const float bA = b_ih[rowA] + b_hh[rowA];
    const float bB = b_ih[rowB] + b_hh[rowB];

    // B-gate activation: r = rcp(1 + exp2(-z*sB)); B = r*mB + aB
    const float sB = upper ? L2E : (2.0f * L2E);
    const float mB = upper ? 1.0f : 2.0f;
    const float aB = upper ? 0.0f : -1.0f;

    const float wout = W_out[j];
    const float bout = b_out[0];

    // phist[s][lane], stride 65: store banks (s+l)%32 conflict-free;
    // flush read phist[l*65+32+k] banks (l+k)%32 conflict-free.
    __shared__ float phist[64 * 65];
    // h-broadcast buffer: slot per lane; upper 32 slots [32..63] hold h_j.
    __shared__ float hbuf[64];

    float c = 0.0f, h = 0.0f;   // state lives in upper lanes
    hbuf[lane] = 0.0f;          // seed broadcast of h_0 = 0
    __syncthreads();

    const float* xb = x + (size_t)b * T_LEN;
    float*       yb = out + (size_t)b * T_LEN;
    // wave-uniform broadcast-read base (h values live at hbuf[32..63])
    const float4* hb4 = reinterpret_cast<const float4*>(&hbuf[32]);

    float xv = xb[lane];  // 64 timesteps of x per lane-chunk

    for (int t0 = 0; t0 < T_LEN; t0 += 64) {
        float xv_next = (t0 + 64 < T_LEN) ? xb[t0 + 64 + lane] : 0.0f;

        #pragma unroll 4
        for (int s = 0; s < 64; ++s) {
            // x contribution: independent of h, schedules off-chain
            const float xs  = rlane(xv, s);
            const float xpA = fmaf(xs, wihA, bA);
            const float xpB = fmaf(xs, wihB, bB);

            // broadcast read: 8x ds_read_b128, wave-uniform addrs, pipelined.
            // hv[q] = {h[4q], h[4q+1], h[4q+2], h[4q+3]} replicated per lane.
            float4 hv[8];
            #pragma unroll
            for (int q = 0; q < 8; ++q) hv[q] = hb4[q];

            // dots: 32 pure-VGPR v_pk_fma_f32, 4-way split accumulators.
            // pair p (p=0..15): {h[2p],h[2p+1]} = xy/zw halves of hv[p/2].
            f2 zA[4], zB[4];
            #pragma unroll
            for (int p = 0; p < 16; ++p) {
                f2 hp;
                if (p & 1) { hp.x = hv[p >> 1].z; hp.y = hv[p >> 1].w; }
                else       { hp.x = hv[p >> 1].x; hp.y = hv[p >> 1].y; }
                if (p < 4) {
                    asm("v_pk_mul_f32 %0, %1, %2"
                        : "=v"(zA[p]) : "v"(hp), "v"(Wa2[p]));
                    asm("v_pk_mul_f32 %0, %1, %2"
                        : "=v"(zB[p]) : "v"(hp), "v"(Wb2[p]));
                } else {
                    asm("v_pk_fma_f32 %0, %1, %2, %0"
                        : "+v"(zA[p & 3]) : "v"(hp), "v"(Wa2[p]));
                    asm("v_pk_fma_f32 %0, %1, %2, %0"
                        : "+v"(zB[p & 3]) : "v"(hp), "v"(Wb2[p]));
                }
            }
            const f2 rA = (zA[0] + zA[1]) + (zA[2] + zA[3]);
            const f2 rB = (zB[0] + zB[1]) + (zB[2] + zB[3]);
            const float za = (rA.x + rA.y) + xpA;
            const float zb = (rB.x + rB.y) + xpB;

            // A = sigmoid(za)  (i on lower, f on upper)
            const float A  = RCPF(1.0f + EXP2F(-za * L2E));
            const float r  = RCPF(1.0f + EXP2F(-zb * sB));
            const float Bv = fmaf(r, mB, aB);  // tanh(g) : sigmoid(o)

            const float u  = A * Bv;           // sig(i)*tanh(g) (lower)
            const float tu = xhalf_lo_to_hi(u);

            c = fmaf(A, c, tu);                // sig(f)*c + u (upper lanes valid)
            const float th = fmaf(2.0f, RCPF(1.0f + EXP2F(-2.0f * L2E * c)), -1.0f);
            h = Bv * th;                       // sig(o)*tanh(c)

            hbuf[lane] = h;                    // publish for next step's reads
            phist[s * 65 + lane] = h * wout;   // deferred output
        }

        __syncthreads();  // single wave: cheap; publish phist
        float acc = bout;
        #pragma unroll
        for (int k = 0; k < HID; ++k) acc += phist[lane * 65 + 32 + k];
        yb[t0 + lane] = acc;
        __syncthreads();  // protect phist before next chunk rewrites it

        xv = xv_next;
    }
}

extern "C" void kernel_launch(void* const* d_in, const int* in_sizes, int n_in,
                              void* d_out, int out_size, void* d_ws, size_t ws_size,
                              hipStream_t stream) {
    const float* x     = (const float*)d_in[0];
    const float* W_ih  = (const float*)d_in[1];
    const float* W_hh  = (const float*)d_in[2];
    const float* b_ih  = (const float*)d_in[3];
    const float* b_hh  = (const float*)d_in[4];
    const float* W_out = (const float*)d_in[5];
    const float* b_out = (const float*)d_in[6];
    float* out = (float*)d_out;

    lstm_seq_kernel<<<BATCH, 64, 0, stream>>>(x, W_ih, W_hh, b_ih, b_hh,
                                              W_out, b_out, out);
}

// Round 12
// 3181.863 us; speedup vs baseline: 1.1732x; 1.0019x over previous
//
#include <hip/hip_runtime.h>

#define T_LEN 16384
#define BATCH 32
#define HID 32
#define L2E 1.44269504088896340736f

typedef float f2 __attribute__((ext_vector_type(2)));

#if __has_builtin(__builtin_amdgcn_exp2f)
#define EXP2F(x) __builtin_amdgcn_exp2f(x)
#else
#define EXP2F(x) __exp2f(x)
#endif
#if __has_builtin(__builtin_amdgcn_rcpf)
#define RCPF(x) __builtin_amdgcn_rcpf(x)
#else
#define RCPF(x) (1.0f / (x))
#endif

__device__ __forceinline__ float rlane(float v, int lane) {
    return __int_as_float(__builtin_amdgcn_readlane(__float_as_int(v), lane));
}

// Cross-half exchange (lower->upper), VALU pipe. Convention verified r4/r5:
// builtin returns {vdst_new, vsrc_new}; r.x has lanes 32-63 = old lanes 0-31.
__device__ __forceinline__ float xhalf_lo_to_hi(float v) {
#if __has_builtin(__builtin_amdgcn_permlane32_swap)
    typedef unsigned u2_t __attribute__((ext_vector_type(2)));
    u2_t r = __builtin_amdgcn_permlane32_swap(__float_as_uint(v), __float_as_uint(v),
                                              false, false);
    return __uint_as_float(r.x);
#else
    return __shfl_xor(v, 32, 64);
#endif
}

// r12 = r11 (LDS-broadcast h, 3188us) with the f2-pair extraction movs
// removed: h is loaded as 16 f2 (ds_read_b64-shaped, wave-uniform broadcast,
// conflict-free) that feed the v_pk_fma_f32 asm operands DIRECTLY — r11
// loaded float4s and built each f2 via component shuffles, which the
// compiler materialized as ~32 v_movs/step (~64 cyc). Also: hbuf publish
// moved to immediately after h (next step's broadcast starts draining
// before the phist work).
__global__ __launch_bounds__(64) __attribute__((amdgpu_waves_per_eu(1, 1)))
void lstm_seq_kernel(const float* __restrict__ x,
                     const float* __restrict__ W_ih,
                     const float* __restrict__ W_hh,
                     const float* __restrict__ b_ih,
                     const float* __restrict__ b_hh,
                     const float* __restrict__ W_out,
                     const float* __restrict__ b_out,
                     float* __restrict__ out)
{
    const int b    = blockIdx.x;
    const int lane = threadIdx.x;
    const int j    = lane & 31;
    const bool upper = (lane >= 32);

    // torch gate order in W_ih/W_hh rows: [0,32)=i [32,64)=f [64,96)=g [96,128)=o
    const int rowA = upper ? (32 + j) : j;        // f : i   (both sigmoid)
    const int rowB = upper ? (96 + j) : (64 + j); // o : g   (sigmoid : tanh)

    // W rows as float2 pairs, pinned resident (r9: VGPR=132, mild win)
    f2 Wa2[16], Wb2[16];
    const f2* ra2 = reinterpret_cast<const f2*>(W_hh + (size_t)rowA * HID);
    const f2* rb2 = reinterpret_cast<const f2*>(W_hh + (size_t)rowB * HID);
    #pragma unroll
    for (int q = 0; q < 16; ++q) { Wa2[q] = ra2[q]; Wb2[q] = rb2[q]; }
    #pragma unroll
    for (int q = 0; q < 16; ++q) { asm("" : "+v"(Wa2[q]), "+v"(Wb2[q])); }

    const float wihA = W_ih[rowA];
    const float wihB = W_ih[rowB];
    const float bA = b_ih[rowA] + b_hh[rowA];
    const float bB = b_ih[rowB] + b_hh[rowB];

    // B-gate activation: r = rcp(1 + exp2(-z*sB)); B = r*mB + aB
    const float sB = upper ? L2E : (2.0f * L2E);
    const float mB = upper ? 1.0f : 2.0f;
    const float aB = upper ? 0.0f : -1.0f;

    const float wout = W_out[j];
    const float bout = b_out[0];

    // phist[s][lane], stride 65: store banks (s+l)%32 conflict-free;
    // flush read phist[l*65+32+k] banks (l+k)%32 conflict-free.
    __shared__ float phist[64 * 65];
    // h-broadcast buffer: slot per lane; upper 32 slots [32..63] hold h_j.
    __shared__ float hbuf[64];

    float c = 0.0f, h = 0.0f;   // state lives in upper lanes
    hbuf[lane] = 0.0f;          // seed broadcast of h_0 = 0
    __syncthreads();

    const float* xb = x + (size_t)b * T_LEN;
    float*       yb = out + (size_t)b * T_LEN;
    // wave-uniform broadcast-read base (h values live at hbuf[32..63]),
    // read as f2 pairs -> register pairs that ARE the pk_fma operands.
    const f2* hb2 = reinterpret_cast<const f2*>(&hbuf[32]);

    float xv = xb[lane];  // 64 timesteps of x per lane-chunk

    for (int t0 = 0; t0 < T_LEN; t0 += 64) {
        float xv_next = (t0 + 64 < T_LEN) ? xb[t0 + 64 + lane] : 0.0f;

        #pragma unroll 4
        for (int s = 0; s < 64; ++s) {
            // x contribution: independent of h, schedules off-chain
            const float xs  = rlane(xv, s);
            const float xpA = fmaf(xs, wihA, bA);
            const float xpB = fmaf(xs, wihB, bB);

            // broadcast read: 16 f2 loads, wave-uniform, conflict-free,
            // pipelined; each lands as an even-aligned VGPR pair.
            f2 hv2[16];
            #pragma unroll
            for (int p = 0; p < 16; ++p) hv2[p] = hb2[p];

            // dots: 32 pure-VGPR v_pk_fma_f32, 4-way split accumulators,
            // operands fed directly from the loaded pairs (no extraction).
            f2 zA[4], zB[4];
            #pragma unroll
            for (int p = 0; p < 16; ++p) {
                if (p < 4) {
                    asm("v_pk_mul_f32 %0, %1, %2"
                        : "=v"(zA[p]) : "v"(hv2[p]), "v"(Wa2[p]));
                    asm("v_pk_mul_f32 %0, %1, %2"
                        : "=v"(zB[p]) : "v"(hv2[p]), "v"(Wb2[p]));
                } else {
                    asm("v_pk_fma_f32 %0, %1, %2, %0"
                        : "+v"(zA[p & 3]) : "v"(hv2[p]), "v"(Wa2[p]));
                    asm("v_pk_fma_f32 %0, %1, %2, %0"
                        : "+v"(zB[p & 3]) : "v"(hv2[p]), "v"(Wb2[p]));
                }
            }
            const f2 rA = (zA[0] + zA[1]) + (zA[2] + zA[3]);
            const f2 rB = (zB[0] + zB[1]) + (zB[2] + zB[3]);
            const float za = (rA.x + rA.y) + xpA;
            const float zb = (rB.x + rB.y) + xpB;

            // A = sigmoid(za)  (i on lower, f on upper)
            const float A  = RCPF(1.0f + EXP2F(-za * L2E));
            const float r  = RCPF(1.0f + EXP2F(-zb * sB));
            const float Bv = fmaf(r, mB, aB);  // tanh(g) : sigmoid(o)

            const float u  = A * Bv;           // sig(i)*tanh(g) (lower)
            const float tu = xhalf_lo_to_hi(u);

            c = fmaf(A, c, tu);                // sig(f)*c + u (upper lanes valid)
            const float th = fmaf(2.0f, RCPF(1.0f + EXP2F(-2.0f * L2E * c)), -1.0f);
            h = Bv * th;                       // sig(o)*tanh(c)

            hbuf[lane] = h;                    // publish FIRST (gates next step)
            phist[s * 65 + lane] = h * wout;   // deferred output (off-chain)
        }

        __syncthreads();  // single wave: cheap; publish phist
        float acc = bout;
        #pragma unroll
        for (int k = 0; k < HID; ++k) acc += phist[lane * 65 + 32 + k];
        yb[t0 + lane] = acc;
        __syncthreads();  // protect phist before next chunk rewrites it

        xv = xv_next;
    }
}

extern "C" void kernel_launch(void* const* d_in, const int* in_sizes, int n_in,
                              void* d_out, int out_size, void* d_ws, size_t ws_size,
                              hipStream_t stream) {
    const float* x     = (const float*)d_in[0];
    const float* W_ih  = (const float*)d_in[1];
    const float* W_hh  = (const float*)d_in[2];
    const float* b_ih  = (const float*)d_in[3];
    const float* b_hh  = (const float*)d_in[4];
    const float* W_out = (const float*)d_in[5];
    const float* b_out = (const float*)d_in[6];
    float* out = (float*)d_out;

    lstm_seq_kernel<<<BATCH, 64, 0, stream>>>(x, W_ih, W_hh, b_ih, b_hh,
                                              W_out, b_out, out);
}